// Round 11
// baseline (18446.384 us; speedup 1.0000x reference)
//
#include <hip/hip_runtime.h>
#include <hip/hip_bf16.h>
#include <math.h>

#define B_  64
#define T_  512
#define I_  512
#define H_  1024
#define G4_ 4096
#define O_  512
#define TC_ 64             // time chunk
#define NCH (T_ / TC_)     // 8
#define WPG 16             // WGs per gbar group

typedef short  s16x8 __attribute__((ext_vector_type(8)));
typedef float  fx4   __attribute__((ext_vector_type(4)));
typedef float  fx8   __attribute__((ext_vector_type(8)));
typedef unsigned short u16;
typedef u16    u16x4 __attribute__((ext_vector_type(4)));
typedef unsigned long long u64t;

__device__ __forceinline__ u16 f2bf(float f){
  unsigned u = __float_as_uint(f);
  unsigned r = u + 0x7fffu + ((u >> 16) & 1u);   // RNE
  return (u16)(r >> 16);
}
__device__ __forceinline__ float bf2f(u16 s){ return __uint_as_float(((unsigned)s) << 16); }
__device__ __forceinline__ float sigm(float x){ return 1.0f / (1.0f + __expf(-x)); }
__device__ __forceinline__ float tanh_(float x){
  float ax = fabsf(x);
  float e  = __expf(2.0f * ax);
  float r  = 1.0f - 2.0f / (e + 1.0f);
  return copysignf(r, x);
}
__device__ __forceinline__ fx4 mfma(s16x8 a, s16x8 b, fx4 c){
  return __builtin_amdgcn_mfma_f32_16x16x32_bf16(a, b, c, 0, 0, 0);
}

// system scope (sc0+sc1): bypass L1+L2, coherent at L3 — cross-XCD exchange
__device__ __forceinline__ u64t aload64(const u16* p){
  return __hip_atomic_load((const u64t*)p, __ATOMIC_RELAXED, __HIP_MEMORY_SCOPE_SYSTEM);
}
__device__ __forceinline__ u64t aload64q(const u64t* p){
  return __hip_atomic_load(p, __ATOMIC_RELAXED, __HIP_MEMORY_SCOPE_SYSTEM);
}
// agent scope (sc0): bypass L1 only, served by local XCD L2 — mirror reads
__device__ __forceinline__ u64t aload64_ag(const u16* p){
  return __hip_atomic_load((const u64t*)p, __ATOMIC_RELAXED, __HIP_MEMORY_SCOPE_AGENT);
}
__device__ __forceinline__ void astore32(u16* p, unsigned v){
  __hip_atomic_store((unsigned*)p, v, __ATOMIC_RELAXED, __HIP_MEMORY_SCOPE_SYSTEM);
}
__device__ __forceinline__ unsigned aload32(const unsigned* p){
  return __hip_atomic_load(p, __ATOMIC_RELAXED, __HIP_MEMORY_SCOPE_SYSTEM);
}
__device__ __forceinline__ unsigned afadd(unsigned* p){
  return __hip_atomic_fetch_add(p, 1u, __ATOMIC_RELAXED, __HIP_MEMORY_SCOPE_SYSTEM);
}

// ---------------- prep kernels ----------------
__global__ void cvt_hilo(const float* __restrict__ src, u16* __restrict__ hi,
                         u16* __restrict__ lo, int n4){
  int i      = blockIdx.x * blockDim.x + threadIdx.x;
  int stride = gridDim.x * blockDim.x;
  for (; i < n4; i += stride){
    fx4 v = ((const fx4*)src)[i];
    u16x4 h, l;
    #pragma unroll
    for (int k = 0; k < 4; ++k){
      u16 hh = f2bf(v[k]);
      h[k] = hh;
      l[k] = f2bf(v[k] - bf2f(hh));
    }
    ((u16x4*)hi)[i] = h;
    ((u16x4*)lo)[i] = l;
  }
}

__global__ void vadd(const float* __restrict__ a, const float* __restrict__ b,
                     float* __restrict__ o, int n){
  int i = blockIdx.x * blockDim.x + threadIdx.x;
  if (i < n) o[i] = a[i] + b[i];
}

// ---------------- bulk GEMM (split-bf16, 128x64 tile) — unchanged ----------------
template<int KD, int AMODE, int OMODE>
__global__ __launch_bounds__(256)
void gemmX(const float* __restrict__ Af,
           const u16* __restrict__ Ah, const u16* __restrict__ Al,
           const u16* __restrict__ Bh, const u16* __restrict__ Bl,
           const float* __restrict__ bias,
           float* __restrict__ out, int N, int c0)
{
  __shared__ float xt[(OMODE == 0) ? 64 * 130 : 4];
  const int lane = threadIdx.x & 63;
  const int wv   = threadIdx.x >> 6;
  const int l15  = lane & 15;
  const int lhi  = lane >> 4;
  const int koff = lhi * 8;
  const int mb   = blockIdx.x * 128;
  const int nb   = blockIdx.y * 64;
  const int r0   = mb + wv * 32 + l15;

  fx4 acc[2][4] = {};
  for (int kt = 0; kt < KD / 32; ++kt){
    const int kb = kt * 32 + koff;
    s16x8 ah[2], al[2];
    #pragma unroll
    for (int mi = 0; mi < 2; ++mi){
      const int r  = r0 + mi * 16;
      const int b  = r & 63;
      const int tl = r >> 6;
      if (AMODE == 0){
        const float* p = Af + ((size_t)b * T_ + c0 + tl) * KD + kb;
        fx8 v = *reinterpret_cast<const fx8*>(p);
        #pragma unroll
        for (int i = 0; i < 8; ++i){
          u16 h = f2bf(v[i]);
          ah[mi][i] = (short)h;
          al[mi][i] = (short)f2bf(v[i] - bf2f(h));
        }
      } else {
        const size_t ao = ((size_t)b * TC_ + tl) * KD + kb;
        ah[mi] = *reinterpret_cast<const s16x8*>(Ah + ao);
        al[mi] = *reinterpret_cast<const s16x8*>(Al + ao);
      }
    }
    #pragma unroll
    for (int c = 0; c < 4; ++c){
      const size_t wo = (size_t)(nb + c * 16 + l15) * KD + kb;
      s16x8 bh = *reinterpret_cast<const s16x8*>(Bh + wo);
      s16x8 bl = *reinterpret_cast<const s16x8*>(Bl + wo);
      #pragma unroll
      for (int mi = 0; mi < 2; ++mi){
        acc[mi][c] = mfma(ah[mi], bh, acc[mi][c]);
        acc[mi][c] = mfma(ah[mi], bl, acc[mi][c]);
        acc[mi][c] = mfma(al[mi], bh, acc[mi][c]);
      }
    }
  }

  if (OMODE == 0){
    #pragma unroll
    for (int c = 0; c < 4; ++c){
      const int nloc = c * 16 + l15;
      const float bv = bias[nb + nloc];
      #pragma unroll
      for (int mi = 0; mi < 2; ++mi)
        #pragma unroll
        for (int r = 0; r < 4; ++r)
          xt[nloc * 130 + wv * 32 + mi * 16 + lhi * 4 + r] = acc[mi][c][r] + bv;
    }
    __syncthreads();
    const int mloc = threadIdx.x & 127;
    const int b    = mloc & 63;
    const int tl   = blockIdx.x * 2 + (mloc >> 6);
    #pragma unroll
    for (int it = 0; it < 32; ++it){
      const int nloc = (threadIdx.x >> 7) + it * 2;
      const int n = nb + nloc;
      const int g = n >> 10;
      const int j = n & 1023;
      out[((size_t)(tl * 4 + g) * H_ + j) * 64 + b] = xt[nloc * 130 + mloc];
    }
  } else {
    #pragma unroll
    for (int c = 0; c < 4; ++c){
      const int n = nb + c * 16 + l15;
      const float bv = bias[n];
      #pragma unroll
      for (int mi = 0; mi < 2; ++mi)
        #pragma unroll
        for (int r = 0; r < 4; ++r){
          const int m  = mb + wv * 32 + mi * 16 + lhi * 4 + r;
          const int b  = m & 63;
          const int tl = m >> 6;
          out[((size_t)b * T_ + c0 + tl) * (size_t)N + n] = acc[mi][c][r] + bv;
        }
    }
  }
}

// ---------------- barriers (relaxed system atomics, r7-proven pattern) ----------
// bar layout (u32): gbar grp cnt [gid*32] (gid<16), top cnt [512], top flag [544],
// grp flags [1024+gid*32]; xcd reg cnt [1600+x*32]; xbar cnt [1856+x*32];
// xbar flag [2112+x*32].
__device__ __forceinline__ void gbar(unsigned* bar, int gid, unsigned ep, int ngrp){
  if (afadd(&bar[gid * 32]) == WPG - 1u){
    __hip_atomic_store(&bar[gid * 32], 0u, __ATOMIC_RELAXED, __HIP_MEMORY_SCOPE_SYSTEM);
    if (afadd(&bar[512]) == (unsigned)(ngrp - 1)){
      __hip_atomic_store(&bar[512], 0u, __ATOMIC_RELAXED, __HIP_MEMORY_SCOPE_SYSTEM);
      astore32((u16*)&bar[544], ep);
    } else {
      while (aload32(&bar[544]) != ep) __builtin_amdgcn_s_sleep(1);
    }
    astore32((u16*)&bar[1024 + gid * 32], ep);
  } else {
    while (aload32(&bar[1024 + gid * 32]) != ep) __builtin_amdgcn_s_sleep(1);
  }
}
__device__ __forceinline__ void xbar(unsigned* bar, int xcd, unsigned ep, int cnt){
  if (afadd(&bar[1856 + xcd * 32]) == (unsigned)(cnt - 1)){
    __hip_atomic_store(&bar[1856 + xcd * 32], 0u, __ATOMIC_RELAXED, __HIP_MEMORY_SCOPE_SYSTEM);
    astore32((u16*)&bar[2112 + xcd * 32], ep);
  } else {
    while (aload32(&bar[2112 + xcd * 32]) != ep) __builtin_amdgcn_s_sleep(1);
  }
}

// copy 256 KB (32768 u64): master (sc1 reads) -> XCD mirror (normal stores)
__device__ __forceinline__ void cpy256k(const u16* src, u16* dst, int i0, int stride){
  const u64t* s = (const u64t*)src;
  u64t* d = (u64t*)dst;
  for (int i = i0; i < 32768; i += stride) d[i] = aload64q(s + i);
}

// ---------------- persistent dual-layer LSTM chunk (LDS-W + XCD mirrors) -------
// WG = 8 units x 4 gates = 32 gate-cols, all 64 rows; 128 WGs/layer.
// W slice (32 cols x 1024 K, hi+lo = 128 KB) staged to LDS once per chunk.
// h exchange: master (sc1) -> gbar -> per-XCD mirror copy (normal stores,
// runtime HW_REG_XCC_ID) -> xbar -> GEMM reads mirror via agent (sc0) loads.
// Master/mirror layout per layer: [par][arr hi/lo][64][1024] u16 (131072/par).
__global__ __launch_bounds__(512)
void lstm_pd(int mode, unsigned ep0, int ngrp,
    const u16* __restrict__ W1h, const u16* __restrict__ W1l,
    const float* __restrict__ xp1, float* __restrict__ cst1,
    u16* __restrict__ hx1, u16* __restrict__ hm1,
    u16* __restrict__ ha1h, u16* __restrict__ ha1l,
    const u16* __restrict__ W2h, const u16* __restrict__ W2l,
    const float* __restrict__ xp2, float* __restrict__ cst2,
    u16* __restrict__ hx2, u16* __restrict__ hm2,
    u16* __restrict__ ha2h, u16* __restrict__ ha2l,
    unsigned* __restrict__ bar)
{
  __shared__ short lw[2][32768];     // [hi/lo][32 cols x 1024 k] swizzled, 128 KB
  __shared__ float red[64 * 65];     // 4-phase reduce buffer, 16.6 KB
  __shared__ int   sx[4];

  int part, bx;
  if (mode == 3){ part = blockIdx.x >> 7; bx = blockIdx.x & 127; }
  else          { part = mode - 1;        bx = blockIdx.x; }
  const int gid = blockIdx.x >> 4;

  const u16*   Wh  = part ? W2h  : W1h;
  const u16*   Wl  = part ? W2l  : W1l;
  const float* xp  = part ? xp2  : xp1;
  float*       cst = part ? cst2 : cst1;
  const u16*   hxL = part ? hx2  : hx1;
  const u16*   hmL = part ? hm2  : hm1;
  u16*         hah = part ? ha2h : ha1h;
  u16*         hal = part ? ha2l : ha1l;

  const int tid  = threadIdx.x;
  const int lane = tid & 63;
  const int wv   = tid >> 6;              // K-slice 0..7
  const int l15  = lane & 15;
  const int lhi  = lane >> 4;
  const int jb8  = bx * 8;                // unit base

  // ---- registration: physical XCD + rank within it ----
  if (tid == 0){
    int xcd;
    asm volatile("s_getreg_b32 %0, hwreg(HW_REG_XCC_ID)" : "=s"(xcd));
    xcd &= 7;
    sx[0] = xcd;
    sx[1] = (int)afadd(&bar[1600 + xcd * 32]);
  }
  __syncthreads();
  const int s_xcd  = sx[0];
  const int s_rank = sx[1];
  if (tid == 0) gbar(bar, gid, ep0 + 1, ngrp);
  __syncthreads();
  if (tid == 0) sx[2] = (int)aload32(&bar[1600 + s_xcd * 32]);
  __syncthreads();
  const int s_cnt = sx[2];

  // ---- stage W slice into LDS (once per chunk), swizzled ----
  // col c in [0,32): gate = (c>>4)*2 + ((c>>3)&1), unit = jb8 + (c&7)
  #pragma unroll
  for (int arr = 0; arr < 2; ++arr){
    const u16* Wg = arr ? Wl : Wh;
    char* dstb = (char*)lw[arr];
    for (int i = tid; i < 4096; i += 512){   // 4096 x 16B = 64 KB
      const int col    = i >> 7;
      const int within = (i & 127) * 16;     // bytes within col row
      const int gate   = ((col >> 4) << 1) | ((col >> 3) & 1);
      const int grow   = gate * H_ + jb8 + (col & 7);
      s16x8 v = *reinterpret_cast<const s16x8*>(Wg + (size_t)grow * H_ + (within >> 1));
      *reinterpret_cast<s16x8*>(dstb + col * 2048 + (within ^ ((col & 7) << 4))) = v;
    }
  }
  __syncthreads();

  // epilogue identity: tid<256 -> (batch row eb, units j0, j0+1)
  const int eb = tid & 63;
  const int e2 = tid >> 6;                // 0..3 when tid<256
  const int j0 = jb8 + 2 * e2;
  float cva = 0.0f, cvb = 0.0f;
  if (tid < 256){
    cva = cst[(size_t)j0 * B_ + eb];
    cvb = cst[(size_t)(j0 + 1) * B_ + eb];
  }

  const int kb0  = wv * 128 + lhi * 8;    // u16 index within k-row
  const int swk0 = wv * 256 + lhi * 16;   // byte offset within col row

  for (int tl = 0; tl < TC_; ++tl){
    const int par = tl & 1;
    const u16* hmR = hmL + ((size_t)s_xcd * 2 + par) * 131072;

    // xp prefetch (overlaps GEMM)
    float xq0[4], xq1[4];
    if (tid < 256){
      #pragma unroll
      for (int g = 0; g < 4; ++g){
        const float* xr = xp + ((size_t)(tl * 4 + g) * H_ + j0) * 64 + eb;
        xq0[g] = xr[0];
        xq1[g] = xr[64];
      }
    }

    // ---- GEMM: h (mirror, agent loads) x W (LDS) ----
    fx4 acc[4][2] = {};
    #pragma unroll
    for (int s = 0; s < 4; ++s){
      const int kb  = kb0 + s * 32;
      const int swk = swk0 + s * 64;
      s16x8 bh[2], bl[2];
      #pragma unroll
      for (int ct = 0; ct < 2; ++ct){
        const int c0  = ct * 16 + l15;
        const int off = c0 * 2048 + (swk ^ ((c0 & 7) << 4));
        bh[ct] = *reinterpret_cast<const s16x8*>((const char*)lw[0] + off);
        bl[ct] = *reinterpret_cast<const s16x8*>((const char*)lw[1] + off);
      }
      #pragma unroll
      for (int mt = 0; mt < 4; ++mt){
        const size_t hb = (size_t)(mt * 16 + l15) * 1024 + kb;
        union { u64t u[2]; s16x8 v; } ua, ul;
        ua.u[0] = aload64_ag(hmR + hb);
        ua.u[1] = aload64_ag(hmR + hb + 4);
        ul.u[0] = aload64_ag(hmR + 65536 + hb);
        ul.u[1] = aload64_ag(hmR + 65536 + hb + 4);
        acc[mt][0] = mfma(ua.v, bh[0], acc[mt][0]);
        acc[mt][0] = mfma(ua.v, bl[0], acc[mt][0]);
        acc[mt][0] = mfma(ul.v, bh[0], acc[mt][0]);
        acc[mt][1] = mfma(ua.v, bh[1], acc[mt][1]);
        acc[mt][1] = mfma(ua.v, bl[1], acc[mt][1]);
        acc[mt][1] = mfma(ul.v, bh[1], acc[mt][1]);
      }
    }

    // ---- 4-phase LDS reduce: phase g == gate g ----
    float sg0[4], sg1[4];
    #pragma unroll
    for (int g = 0; g < 4; ++g){
      const int ct = g >> 1, half = g & 1;
      if ((l15 >> 3) == half){
        #pragma unroll
        for (int mt = 0; mt < 4; ++mt)
          #pragma unroll
          for (int r = 0; r < 4; ++r)
            red[(mt * 16 + lhi * 4 + r) * 65 + (l15 & 7) * 8 + wv] = acc[mt][ct][r];
      }
      __syncthreads();
      if (tid < 256){
        const float* r0 = red + eb * 65 + (2 * e2) * 8;
        const float* r1 = red + eb * 65 + (2 * e2 + 1) * 8;
        float s0 = 0, s1 = 0;
        #pragma unroll
        for (int w = 0; w < 8; ++w){ s0 += r0[w]; s1 += r1[w]; }
        sg0[g] = s0; sg1[g] = s1;
      }
      __syncthreads();
    }

    // ---- epilogue: gates, state update, master + archive writes ----
    if (tid < 256){
      float iv = sigm (sg0[0] + xq0[0]);
      float fv = sigm (sg0[1] + xq0[1]);
      float gv = tanh_(sg0[2] + xq0[2]);
      float ov = sigm (sg0[3] + xq0[3]);
      float cn = fv * cva + iv * gv;
      float h0 = ov * tanh_(cn);
      cva = cn;
      iv = sigm (sg1[0] + xq1[0]);
      fv = sigm (sg1[1] + xq1[1]);
      gv = tanh_(sg1[2] + xq1[2]);
      ov = sigm (sg1[3] + xq1[3]);
      cn = fv * cvb + iv * gv;
      float h1 = ov * tanh_(cn);
      cvb = cn;

      u16 h0h = f2bf(h0), h0l = f2bf(h0 - bf2f(h0h));
      u16 h1h = f2bf(h1), h1l = f2bf(h1 - bf2f(h1h));
      u16* mh = (u16*)hxL + (size_t)(par ^ 1) * 131072 + (size_t)eb * 1024 + j0;
      astore32(mh,         (unsigned)h0h | ((unsigned)h1h << 16));
      astore32(mh + 65536, (unsigned)h0l | ((unsigned)h1l << 16));
      const size_t ai = ((size_t)eb * TC_ + tl) * H_ + j0;
      *(unsigned*)(hah + ai) = (unsigned)h0h | ((unsigned)h1h << 16);
      *(unsigned*)(hal + ai) = (unsigned)h0l | ((unsigned)h1l << 16);
    }

    __syncthreads();                      // drain master writes (vmcnt)
    if (tid == 0) gbar(bar, gid, ep0 + 2 + tl, ngrp);
    __syncthreads();

    // ---- stage B: master[par^1] -> my XCD mirror[par^1] (both active layers) --
    {
      const int i0 = s_rank * 512 + tid;
      const int st = s_cnt * 512;
      if (mode & 1)
        cpy256k(hx1 + (size_t)(par ^ 1) * 131072,
                hm1 + ((size_t)s_xcd * 2 + (par ^ 1)) * 131072, i0, st);
      if (mode & 2)
        cpy256k(hx2 + (size_t)(par ^ 1) * 131072,
                hm2 + ((size_t)s_xcd * 2 + (par ^ 1)) * 131072, i0, st);
    }
    __syncthreads();                      // drain mirror writes into local L2
    if (tid == 0) xbar(bar, s_xcd, ep0 + 2 + tl, s_cnt);
    __syncthreads();
  }

  if (tid < 256){
    cst[(size_t)j0 * B_ + eb]       = cva;
    cst[(size_t)(j0 + 1) * B_ + eb] = cvb;
  }
  // reset registration counter for the next chunk launch
  if (s_rank == 0 && tid == 0)
    __hip_atomic_store(&bar[1600 + s_xcd * 32], 0u, __ATOMIC_RELAXED,
                       __HIP_MEMORY_SCOPE_SYSTEM);
}

// ---------------- host launch ----------------
extern "C" void kernel_launch(void* const* d_in, const int* in_sizes, int n_in,
                              void* d_out, int out_size, void* d_ws, size_t ws_size,
                              hipStream_t stream)
{
  const float* x    = (const float*)d_in[0];
  const float* Wih1 = (const float*)d_in[1];
  const float* Whh1 = (const float*)d_in[2];
  const float* bih1 = (const float*)d_in[3];
  const float* bhh1 = (const float*)d_in[4];
  const float* Wih2 = (const float*)d_in[5];
  const float* Whh2 = (const float*)d_in[6];
  const float* bih2 = (const float*)d_in[7];
  const float* bhh2 = (const float*)d_in[8];
  const float* fcW  = (const float*)d_in[9];
  const float* fcb  = (const float*)d_in[10];
  float* out = (float*)d_out;
  (void)in_sizes; (void)n_in; (void)out_size; (void)ws_size;

  char* base = (char*)d_ws;
  size_t off = 0;
  auto alloc = [&](size_t bytes) -> void* {
    void* p = base + off;
    off = (off + bytes + 255) & ~(size_t)255;
    return p;
  };
  u16* Wih1_hi = (u16*)alloc((size_t)G4_ * I_ * 2);
  u16* Wih1_lo = (u16*)alloc((size_t)G4_ * I_ * 2);
  u16* Whh1_hi = (u16*)alloc((size_t)G4_ * H_ * 2);
  u16* Whh1_lo = (u16*)alloc((size_t)G4_ * H_ * 2);
  u16* Wih2_hi = (u16*)alloc((size_t)G4_ * H_ * 2);
  u16* Wih2_lo = (u16*)alloc((size_t)G4_ * H_ * 2);
  u16* Whh2_hi = (u16*)alloc((size_t)G4_ * H_ * 2);
  u16* Whh2_lo = (u16*)alloc((size_t)G4_ * H_ * 2);
  u16* fcW_hi  = (u16*)alloc((size_t)O_ * H_ * 2);
  u16* fcW_lo  = (u16*)alloc((size_t)O_ * H_ * 2);
  float* bsum1 = (float*)alloc((size_t)G4_ * 4);
  float* bsum2 = (float*)alloc((size_t)G4_ * 4);
  float* cst1  = (float*)alloc((size_t)B_ * H_ * 4);
  float* cst2  = (float*)alloc((size_t)B_ * H_ * 4);
  u16* hx1 = (u16*)alloc((size_t)2 * 2 * B_ * H_ * 2);        // master [par][arr][64][1024]
  u16* hx2 = (u16*)alloc((size_t)2 * 2 * B_ * H_ * 2);
  u16* hm1 = (u16*)alloc((size_t)8 * 2 * 2 * B_ * H_ * 2);    // mirrors [xcd][par][...]
  u16* hm2 = (u16*)alloc((size_t)8 * 2 * 2 * B_ * H_ * 2);
  u16* h1s_hi = (u16*)alloc((size_t)B_ * TC_ * H_ * 2);
  u16* h1s_lo = (u16*)alloc((size_t)B_ * TC_ * H_ * 2);
  u16* h2s_hi = (u16*)alloc((size_t)B_ * TC_ * H_ * 2);
  u16* h2s_lo = (u16*)alloc((size_t)B_ * TC_ * H_ * 2);
  float* xp1  = (float*)alloc((size_t)TC_ * G4_ * B_ * 4);
  float* xp2  = (float*)alloc((size_t)TC_ * G4_ * B_ * 4);
  unsigned* bar = (unsigned*)alloc(4096 * 4);

  // ---- prep ----
  cvt_hilo<<<512, 256, 0, stream>>>(Wih1, Wih1_hi, Wih1_lo, G4_ * I_ / 4);
  cvt_hilo<<<512, 256, 0, stream>>>(Whh1, Whh1_hi, Whh1_lo, G4_ * H_ / 4);
  cvt_hilo<<<512, 256, 0, stream>>>(Wih2, Wih2_hi, Wih2_lo, G4_ * H_ / 4);
  cvt_hilo<<<512, 256, 0, stream>>>(Whh2, Whh2_hi, Whh2_lo, G4_ * H_ / 4);
  cvt_hilo<<<256, 256, 0, stream>>>(fcW,  fcW_hi,  fcW_lo,  O_ * H_ / 4);
  vadd<<<16, 256, 0, stream>>>(bih1, bhh1, bsum1, G4_);
  vadd<<<16, 256, 0, stream>>>(bih2, bhh2, bsum2, G4_);

  hipMemsetAsync(cst1, 0, (size_t)B_ * H_ * 4, stream);
  hipMemsetAsync(cst2, 0, (size_t)B_ * H_ * 4, stream);
  hipMemsetAsync(hx1,  0, (size_t)2 * 2 * B_ * H_ * 2, stream);
  hipMemsetAsync(hx2,  0, (size_t)2 * 2 * B_ * H_ * 2, stream);
  hipMemsetAsync(hm1,  0, (size_t)8 * 2 * 2 * B_ * H_ * 2, stream);
  hipMemsetAsync(hm2,  0, (size_t)8 * 2 * 2 * B_ * H_ * 2, stream);
  hipMemsetAsync(bar,  0, 4096 * 4, stream);

  const dim3 gX(32, 64);
  const dim3 gF(32, 8);

  gemmX<I_, 0, 0><<<gX, 256, 0, stream>>>(
      x, nullptr, nullptr, Wih1_hi, Wih1_lo, bsum1, xp1, G4_, 0);

  unsigned ep = 0;
  for (int c = 0; c <= NCH; ++c){
    const int mode = ((c < NCH) ? 1 : 0) | ((c >= 1) ? 2 : 0);
    const int nwg  = (mode == 3) ? 256 : 128;
    int ngrp = nwg / WPG;
    {
      void* args[] = { (void*)&mode, (void*)&ep, (void*)&ngrp,
                       (void*)&Whh1_hi, (void*)&Whh1_lo, (void*)&xp1, (void*)&cst1,
                       (void*)&hx1, (void*)&hm1, (void*)&h1s_hi, (void*)&h1s_lo,
                       (void*)&Whh2_hi, (void*)&Whh2_lo, (void*)&xp2, (void*)&cst2,
                       (void*)&hx2, (void*)&hm2, (void*)&h2s_hi, (void*)&h2s_lo,
                       (void*)&bar };
      hipLaunchCooperativeKernel((const void*)lstm_pd, dim3(nwg), dim3(512),
                                 args, 0, stream);
      ep += TC_ + 2;
    }
    if (c < NCH)
      gemmX<H_, 1, 0><<<gX, 256, 0, stream>>>(
          nullptr, h1s_hi, h1s_lo, Wih2_hi, Wih2_lo, bsum2, xp2, G4_, 0);
    if (c + 1 < NCH)
      gemmX<I_, 0, 0><<<gX, 256, 0, stream>>>(
          x, nullptr, nullptr, Wih1_hi, Wih1_lo, bsum1, xp1, G4_, (c + 1) * TC_);
    if (c >= 1)
      gemmX<H_, 1, 1><<<gF, 256, 0, stream>>>(
          nullptr, h2s_hi, h2s_lo, fcW_hi, fcW_lo, fcb, out, O_, (c - 1) * TC_);
  }
}

// Round 12
// 13641.898 us; speedup vs baseline: 1.3522x; 1.3522x over previous
//
#include <hip/hip_runtime.h>
#include <hip/hip_bf16.h>
#include <math.h>

#define B_  64
#define T_  512
#define I_  512
#define H_  1024
#define G4_ 4096
#define O_  512
#define TC_ 64             // time chunk
#define NCH (T_ / TC_)     // 8
#define WPG 16             // WGs per gbar group

typedef short  s16x8 __attribute__((ext_vector_type(8)));
typedef float  fx4   __attribute__((ext_vector_type(4)));
typedef float  fx8   __attribute__((ext_vector_type(8)));
typedef unsigned short u16;
typedef u16    u16x4 __attribute__((ext_vector_type(4)));
typedef unsigned long long u64t;

__device__ __forceinline__ u16 f2bf(float f){
  unsigned u = __float_as_uint(f);
  unsigned r = u + 0x7fffu + ((u >> 16) & 1u);   // RNE
  return (u16)(r >> 16);
}
__device__ __forceinline__ float bf2f(u16 s){ return __uint_as_float(((unsigned)s) << 16); }
__device__ __forceinline__ float sigm(float x){ return 1.0f / (1.0f + __expf(-x)); }
__device__ __forceinline__ float tanh_(float x){
  float ax = fabsf(x);
  float e  = __expf(2.0f * ax);
  float r  = 1.0f - 2.0f / (e + 1.0f);
  return copysignf(r, x);
}
__device__ __forceinline__ fx4 mfma(s16x8 a, s16x8 b, fx4 c){
  return __builtin_amdgcn_mfma_f32_16x16x32_bf16(a, b, c, 0, 0, 0);
}

// system-scope relaxed atomics (sc0+sc1): bypass L1+L2 -> coherent at L3; cheap
__device__ __forceinline__ u64t aload64(const u16* p){
  return __hip_atomic_load((const u64t*)p, __ATOMIC_RELAXED, __HIP_MEMORY_SCOPE_SYSTEM);
}
__device__ __forceinline__ void astore32(u16* p, unsigned v){
  __hip_atomic_store((unsigned*)p, v, __ATOMIC_RELAXED, __HIP_MEMORY_SCOPE_SYSTEM);
}
__device__ __forceinline__ unsigned aload32(const unsigned* p){
  return __hip_atomic_load(p, __ATOMIC_RELAXED, __HIP_MEMORY_SCOPE_SYSTEM);
}
__device__ __forceinline__ unsigned afadd(unsigned* p){
  return __hip_atomic_fetch_add(p, 1u, __ATOMIC_RELAXED, __HIP_MEMORY_SCOPE_SYSTEM);
}

// ---------------- prep kernels ----------------
__global__ void cvt_hilo(const float* __restrict__ src, u16* __restrict__ hi,
                         u16* __restrict__ lo, int n4){
  int i      = blockIdx.x * blockDim.x + threadIdx.x;
  int stride = gridDim.x * blockDim.x;
  for (; i < n4; i += stride){
    fx4 v = ((const fx4*)src)[i];
    u16x4 h, l;
    #pragma unroll
    for (int k = 0; k < 4; ++k){
      u16 hh = f2bf(v[k]);
      h[k] = hh;
      l[k] = f2bf(v[k] - bf2f(hh));
    }
    ((u16x4*)hi)[i] = h;
    ((u16x4*)lo)[i] = l;
  }
}

__global__ void vadd(const float* __restrict__ a, const float* __restrict__ b,
                     float* __restrict__ o, int n){
  int i = blockIdx.x * blockDim.x + threadIdx.x;
  if (i < n) o[i] = a[i] + b[i];
}

// ---------------- bulk GEMM (split-bf16, 128x64 tile) — unchanged ----------------
template<int KD, int AMODE, int OMODE>
__global__ __launch_bounds__(256)
void gemmX(const float* __restrict__ Af,
           const u16* __restrict__ Ah, const u16* __restrict__ Al,
           const u16* __restrict__ Bh, const u16* __restrict__ Bl,
           const float* __restrict__ bias,
           float* __restrict__ out, int N, int c0)
{
  __shared__ float xt[(OMODE == 0) ? 64 * 130 : 4];
  const int lane = threadIdx.x & 63;
  const int wv   = threadIdx.x >> 6;
  const int l15  = lane & 15;
  const int lhi  = lane >> 4;
  const int koff = lhi * 8;
  const int mb   = blockIdx.x * 128;
  const int nb   = blockIdx.y * 64;
  const int r0   = mb + wv * 32 + l15;

  fx4 acc[2][4] = {};
  for (int kt = 0; kt < KD / 32; ++kt){
    const int kb = kt * 32 + koff;
    s16x8 ah[2], al[2];
    #pragma unroll
    for (int mi = 0; mi < 2; ++mi){
      const int r  = r0 + mi * 16;
      const int b  = r & 63;
      const int tl = r >> 6;
      if (AMODE == 0){
        const float* p = Af + ((size_t)b * T_ + c0 + tl) * KD + kb;
        fx8 v = *reinterpret_cast<const fx8*>(p);
        #pragma unroll
        for (int i = 0; i < 8; ++i){
          u16 h = f2bf(v[i]);
          ah[mi][i] = (short)h;
          al[mi][i] = (short)f2bf(v[i] - bf2f(h));
        }
      } else {
        const size_t ao = ((size_t)b * TC_ + tl) * KD + kb;
        ah[mi] = *reinterpret_cast<const s16x8*>(Ah + ao);
        al[mi] = *reinterpret_cast<const s16x8*>(Al + ao);
      }
    }
    #pragma unroll
    for (int c = 0; c < 4; ++c){
      const size_t wo = (size_t)(nb + c * 16 + l15) * KD + kb;
      s16x8 bh = *reinterpret_cast<const s16x8*>(Bh + wo);
      s16x8 bl = *reinterpret_cast<const s16x8*>(Bl + wo);
      #pragma unroll
      for (int mi = 0; mi < 2; ++mi){
        acc[mi][c] = mfma(ah[mi], bh, acc[mi][c]);
        acc[mi][c] = mfma(ah[mi], bl, acc[mi][c]);
        acc[mi][c] = mfma(al[mi], bh, acc[mi][c]);
      }
    }
  }

  if (OMODE == 0){
    #pragma unroll
    for (int c = 0; c < 4; ++c){
      const int nloc = c * 16 + l15;
      const float bv = bias[nb + nloc];
      #pragma unroll
      for (int mi = 0; mi < 2; ++mi)
        #pragma unroll
        for (int r = 0; r < 4; ++r)
          xt[nloc * 130 + wv * 32 + mi * 16 + lhi * 4 + r] = acc[mi][c][r] + bv;
    }
    __syncthreads();
    const int mloc = threadIdx.x & 127;
    const int b    = mloc & 63;
    const int tl   = blockIdx.x * 2 + (mloc >> 6);
    #pragma unroll
    for (int it = 0; it < 32; ++it){
      const int nloc = (threadIdx.x >> 7) + it * 2;
      const int n = nb + nloc;
      const int g = n >> 10;
      const int j = n & 1023;
      out[((size_t)(tl * 4 + g) * H_ + j) * 64 + b] = xt[nloc * 130 + mloc];
    }
  } else {
    #pragma unroll
    for (int c = 0; c < 4; ++c){
      const int n = nb + c * 16 + l15;
      const float bv = bias[n];
      #pragma unroll
      for (int mi = 0; mi < 2; ++mi)
        #pragma unroll
        for (int r = 0; r < 4; ++r){
          const int m  = mb + wv * 32 + mi * 16 + lhi * 4 + r;
          const int b  = m & 63;
          const int tl = m >> 6;
          out[((size_t)b * T_ + c0 + tl) * (size_t)N + n] = acc[mi][c][r] + bv;
        }
    }
  }
}

// ---------------- two-level grid barrier (relaxed atomics, r7-proven) ----------
// bar (u32): grp cnt [gid*32] gid<16, top cnt [512], top flag [544],
// grp flags [1024+gid*32]; XCD reg counters [1600+x*32]; imbalance flag [2560].
__device__ __forceinline__ void gbar(unsigned* bar, int gid, unsigned ep, int ngrp){
  if (afadd(&bar[gid * 32]) == WPG - 1u){
    __hip_atomic_store(&bar[gid * 32], 0u, __ATOMIC_RELAXED, __HIP_MEMORY_SCOPE_SYSTEM);
    if (afadd(&bar[512]) == (unsigned)(ngrp - 1)){
      __hip_atomic_store(&bar[512], 0u, __ATOMIC_RELAXED, __HIP_MEMORY_SCOPE_SYSTEM);
      astore32((u16*)&bar[544], ep);
    } else {
      while (aload32(&bar[544]) != ep) __builtin_amdgcn_s_sleep(1);
    }
    astore32((u16*)&bar[1024 + gid * 32], ep);
  } else {
    while (aload32(&bar[1024 + gid * 32]) != ep) __builtin_amdgcn_s_sleep(1);
  }
}

// ---------------- persistent dual-layer LSTM chunk (XCD-local W) ----------------
// Decomposition (r8/r10): WG = (layer, M-tile of 16 rows, 32 units x 4 gates =
// 128 gate-cols); 8 waves K-split K=1024. NEW: work id comes from runtime XCD
// registration (HW_REG_XCC_ID + per-XCD rank). If every XCD hosts exactly
// nwg/8 WGs (cooperative 1-WG/CU), wid = xcd*q + rank and the decode below
// puts ONE layer x 8 unit-groups on each XCD -> unique W/XCD = 4 MB =
// L2-resident for the whole chunk. Otherwise falls back to wid = blockIdx
// (same decode -> still correct, just loses locality). W is streamed (no
// register-residency games — r9/r10 proved the allocator won't hold it).
#define RSTR 577   // LDS reduce row stride (col stride 9, coprime with 32 banks)
__global__ __launch_bounds__(512)
void lstm_pd(int mode, unsigned ep0, int ngrp,
    const u16* __restrict__ W1h, const u16* __restrict__ W1l,
    const float* __restrict__ xp1, float* __restrict__ cst1,
    u16* __restrict__ hx1h, u16* __restrict__ hx1l,
    u16* __restrict__ ha1h, u16* __restrict__ ha1l,
    const u16* __restrict__ W2h, const u16* __restrict__ W2l,
    const float* __restrict__ xp2, float* __restrict__ cst2,
    u16* __restrict__ hx2h, u16* __restrict__ hx2l,
    u16* __restrict__ ha2h, u16* __restrict__ ha2l,
    unsigned* __restrict__ bar)
{
  __shared__ float red[16 * RSTR];
  __shared__ int sx[4];

  const int tid = threadIdx.x;
  const int gid = blockIdx.x >> 4;

  // ---- registration: physical XCD + rank ----
  if (tid == 0){
    int xcd;
    asm volatile("s_getreg_b32 %0, hwreg(HW_REG_XCC_ID)" : "=s"(xcd));
    xcd &= 7;
    sx[0] = xcd;
    sx[1] = (int)afadd(&bar[1600 + xcd * 32]);
  }
  __syncthreads();
  const int s_xcd  = sx[0];
  const int s_rank = sx[1];
  if (tid == 0) gbar(bar, gid, ep0 + 1, ngrp);     // all registrations visible
  const int q = ngrp * 2;                          // expected WGs per XCD (nwg/8)
  if (tid == 0){
    if ((int)aload32(&bar[1600 + s_xcd * 32]) != q) afadd(&bar[2560]);
  }
  if (tid == 0) gbar(bar, gid, ep0 + 2, ngrp);     // all imbalance marks visible
  __syncthreads();
  if (tid == 0) sx[2] = (int)aload32(&bar[2560]);
  __syncthreads();
  const int wid = (sx[2] == 0) ? (s_xcd * q + s_rank) : (int)blockIdx.x;

  // ---- decode work: XCD-major -> one XCD = one layer x 8 unit-groups ----
  int part, bx;
  if (mode == 3){ part = wid >> 7; bx = wid & 127; }
  else          { part = mode - 1; bx = wid; }
  const int m4 = bx & 3;                  // M-tile
  const int ug = bx >> 2;                 // unit-group 0..31 (32 units each)
  const int jb = ug * 32;
  const int mb = m4 * 16;

  const u16*   Wh  = part ? W2h  : W1h;
  const u16*   Wl  = part ? W2l  : W1l;
  const float* xp  = part ? xp2  : xp1;
  float*       cst = part ? cst2 : cst1;
  u16*         hxh = part ? hx2h : hx1h;
  u16*         hxl = part ? hx2l : hx1l;
  u16*         hah = part ? ha2h : ha1h;
  u16*         hal = part ? ha2l : ha1l;

  const int lane = tid & 63;
  const int wv   = tid >> 6;              // K-slice 0..7
  const int l15  = lane & 15;
  const int lhi  = lane >> 4;
  const int kb0  = wv * 128 + lhi * 8;

  // W rows for the 8 coltiles: cl = ct*16+l15; gate = cl>>5; unit = jb+(cl&31)
  size_t wrow[8];
  #pragma unroll
  for (int ct = 0; ct < 8; ++ct){
    const int cl = ct * 16 + l15;
    wrow[ct] = (size_t)((cl >> 5) * H_ + jb + (cl & 31));
  }

  // epilogue identity: tid<256 -> (batch row, unit pair)
  const int up = tid & 15;
  const int mm = tid >> 4;                // 0..15 when tid<256
  const int u0 = 2 * up;
  const int j0 = jb + u0;
  const int eb = mb + mm;
  float cva = 0.0f, cvb = 0.0f;
  if (tid < 256){
    cva = cst[(size_t)j0 * B_ + eb];
    cvb = cst[(size_t)(j0 + 1) * B_ + eb];
  }

  for (int tl = 0; tl < TC_; ++tl){
    const int par = tl & 1;
    const u16* rph = hxh + par * (64 * H_);
    const u16* rpl = hxl + par * (64 * H_);
    u16* nph = hxh + (par ^ 1) * (64 * H_);
    u16* npl = hxl + (par ^ 1) * (64 * H_);

    float xq0[4], xq1[4];
    if (tid < 256){
      #pragma unroll
      for (int g = 0; g < 4; ++g){
        const float* xr = xp + ((size_t)(tl * 4 + g) * H_ + j0) * 64 + eb;
        xq0[g] = xr[0];
        xq1[g] = xr[64];
      }
    }

    // ---- GEMM: h[16 rows] x W[128 cols] (W streamed, L2-local) ----
    fx4 acc[8] = {};
    #pragma unroll
    for (int s = 0; s < 4; ++s){
      const int kb = kb0 + s * 32;
      const u16* ph = rph + (size_t)(mb + l15) * H_ + kb;
      const u16* pl = rpl + (size_t)(mb + l15) * H_ + kb;
      union { u64t u[2]; s16x8 v; } ua, ul;
      ua.u[0] = aload64(ph);  ua.u[1] = aload64(ph + 4);
      ul.u[0] = aload64(pl);  ul.u[1] = aload64(pl + 4);
      #pragma unroll
      for (int ct = 0; ct < 8; ++ct){
        const size_t wo = wrow[ct] * H_ + kb;
        s16x8 bh = *reinterpret_cast<const s16x8*>(Wh + wo);
        s16x8 bl = *reinterpret_cast<const s16x8*>(Wl + wo);
        acc[ct] = mfma(ua.v, bh, acc[ct]);
        acc[ct] = mfma(ua.v, bl, acc[ct]);
        acc[ct] = mfma(ul.v, bh, acc[ct]);
      }
    }

    // ---- phase A reduce: coltiles 0-3 (gates i,f) ----
    #pragma unroll
    for (int ct = 0; ct < 4; ++ct)
      #pragma unroll
      for (int r = 0; r < 4; ++r)
        red[(lhi * 4 + r) * RSTR + (ct * 16 + l15) * 9 + wv] = acc[ct][r];
    __syncthreads();
    float i0s = 0, i1s = 0, f0s = 0, f1s = 0;
    if (tid < 256){
      const float* r0 = red + mm * RSTR + (u0) * 9;
      const float* r1 = red + mm * RSTR + (u0 + 1) * 9;
      const float* r2 = red + mm * RSTR + (32 + u0) * 9;
      const float* r3 = red + mm * RSTR + (32 + u0 + 1) * 9;
      #pragma unroll
      for (int w = 0; w < 8; ++w){
        i0s += r0[w]; i1s += r1[w]; f0s += r2[w]; f1s += r3[w];
      }
    }
    __syncthreads();

    // ---- phase B reduce: coltiles 4-7 (gates g,o) ----
    #pragma unroll
    for (int ct = 0; ct < 4; ++ct)
      #pragma unroll
      for (int r = 0; r < 4; ++r)
        red[(lhi * 4 + r) * RSTR + (ct * 16 + l15) * 9 + wv] = acc[4 + ct][r];
    __syncthreads();

    if (tid < 256){
      float g0s = 0, g1s = 0, o0s = 0, o1s = 0;
      const float* r0 = red + mm * RSTR + (u0) * 9;
      const float* r1 = red + mm * RSTR + (u0 + 1) * 9;
      const float* r2 = red + mm * RSTR + (32 + u0) * 9;
      const float* r3 = red + mm * RSTR + (32 + u0 + 1) * 9;
      #pragma unroll
      for (int w = 0; w < 8; ++w){
        g0s += r0[w]; g1s += r1[w]; o0s += r2[w]; o1s += r3[w];
      }
      float iv = sigm (i0s + xq0[0]);
      float fv = sigm (f0s + xq0[1]);
      float gv = tanh_(g0s + xq0[2]);
      float ov = sigm (o0s + xq0[3]);
      float cn = fv * cva + iv * gv;
      float h0 = ov * tanh_(cn);
      cva = cn;
      iv = sigm (i1s + xq1[0]);
      fv = sigm (f1s + xq1[1]);
      gv = tanh_(g1s + xq1[2]);
      ov = sigm (o1s + xq1[3]);
      cn = fv * cvb + iv * gv;
      float h1 = ov * tanh_(cn);
      cvb = cn;

      u16 h0h = f2bf(h0), h0l = f2bf(h0 - bf2f(h0h));
      u16 h1h = f2bf(h1), h1l = f2bf(h1 - bf2f(h1h));
      astore32(nph + (size_t)eb * H_ + j0, (unsigned)h0h | ((unsigned)h1h << 16));
      astore32(npl + (size_t)eb * H_ + j0, (unsigned)h0l | ((unsigned)h1l << 16));
      const size_t ai = ((size_t)eb * TC_ + tl) * H_ + j0;
      *(unsigned*)(hah + ai) = (unsigned)h0h | ((unsigned)h1h << 16);
      *(unsigned*)(hal + ai) = (unsigned)h0l | ((unsigned)h1l << 16);
    }

    __syncthreads();                      // drains vmcnt before signal
    if (tid == 0) gbar(bar, gid, ep0 + 3 + tl, ngrp);
    __syncthreads();
  }
  if (tid < 256){
    cst[(size_t)j0 * B_ + eb]       = cva;
    cst[(size_t)(j0 + 1) * B_ + eb] = cvb;
  }
  // reset registration state for the next chunk launch
  if (tid == 0 && s_rank == 0)
    __hip_atomic_store(&bar[1600 + s_xcd * 32], 0u, __ATOMIC_RELAXED,
                       __HIP_MEMORY_SCOPE_SYSTEM);
  if (tid == 0 && blockIdx.x == 0)
    __hip_atomic_store(&bar[2560], 0u, __ATOMIC_RELAXED, __HIP_MEMORY_SCOPE_SYSTEM);
}

// ---------------- host launch ----------------
extern "C" void kernel_launch(void* const* d_in, const int* in_sizes, int n_in,
                              void* d_out, int out_size, void* d_ws, size_t ws_size,
                              hipStream_t stream)
{
  const float* x    = (const float*)d_in[0];
  const float* Wih1 = (const float*)d_in[1];
  const float* Whh1 = (const float*)d_in[2];
  const float* bih1 = (const float*)d_in[3];
  const float* bhh1 = (const float*)d_in[4];
  const float* Wih2 = (const float*)d_in[5];
  const float* Whh2 = (const float*)d_in[6];
  const float* bih2 = (const float*)d_in[7];
  const float* bhh2 = (const float*)d_in[8];
  const float* fcW  = (const float*)d_in[9];
  const float* fcb  = (const float*)d_in[10];
  float* out = (float*)d_out;
  (void)in_sizes; (void)n_in; (void)out_size; (void)ws_size;

  char* base = (char*)d_ws;
  size_t off = 0;
  auto alloc = [&](size_t bytes) -> void* {
    void* p = base + off;
    off = (off + bytes + 255) & ~(size_t)255;
    return p;
  };
  u16* Wih1_hi = (u16*)alloc((size_t)G4_ * I_ * 2);
  u16* Wih1_lo = (u16*)alloc((size_t)G4_ * I_ * 2);
  u16* Whh1_hi = (u16*)alloc((size_t)G4_ * H_ * 2);
  u16* Whh1_lo = (u16*)alloc((size_t)G4_ * H_ * 2);
  u16* Wih2_hi = (u16*)alloc((size_t)G4_ * H_ * 2);
  u16* Wih2_lo = (u16*)alloc((size_t)G4_ * H_ * 2);
  u16* Whh2_hi = (u16*)alloc((size_t)G4_ * H_ * 2);
  u16* Whh2_lo = (u16*)alloc((size_t)G4_ * H_ * 2);
  u16* fcW_hi  = (u16*)alloc((size_t)O_ * H_ * 2);
  u16* fcW_lo  = (u16*)alloc((size_t)O_ * H_ * 2);
  float* bsum1 = (float*)alloc((size_t)G4_ * 4);
  float* bsum2 = (float*)alloc((size_t)G4_ * 4);
  float* cst1  = (float*)alloc((size_t)B_ * H_ * 4);
  float* cst2  = (float*)alloc((size_t)B_ * H_ * 4);
  u16* hx1h = (u16*)alloc((size_t)2 * B_ * H_ * 2);   // [par][64][1024]
  u16* hx1l = (u16*)alloc((size_t)2 * B_ * H_ * 2);
  u16* hx2h = (u16*)alloc((size_t)2 * B_ * H_ * 2);
  u16* hx2l = (u16*)alloc((size_t)2 * B_ * H_ * 2);
  u16* h1s_hi = (u16*)alloc((size_t)B_ * TC_ * H_ * 2);
  u16* h1s_lo = (u16*)alloc((size_t)B_ * TC_ * H_ * 2);
  u16* h2s_hi = (u16*)alloc((size_t)B_ * TC_ * H_ * 2);
  u16* h2s_lo = (u16*)alloc((size_t)B_ * TC_ * H_ * 2);
  float* xp1  = (float*)alloc((size_t)TC_ * G4_ * B_ * 4);
  float* xp2  = (float*)alloc((size_t)TC_ * G4_ * B_ * 4);
  unsigned* bar = (unsigned*)alloc(4096 * 4);

  // ---- prep ----
  cvt_hilo<<<512, 256, 0, stream>>>(Wih1, Wih1_hi, Wih1_lo, G4_ * I_ / 4);
  cvt_hilo<<<512, 256, 0, stream>>>(Whh1, Whh1_hi, Whh1_lo, G4_ * H_ / 4);
  cvt_hilo<<<512, 256, 0, stream>>>(Wih2, Wih2_hi, Wih2_lo, G4_ * H_ / 4);
  cvt_hilo<<<512, 256, 0, stream>>>(Whh2, Whh2_hi, Whh2_lo, G4_ * H_ / 4);
  cvt_hilo<<<256, 256, 0, stream>>>(fcW,  fcW_hi,  fcW_lo,  O_ * H_ / 4);
  vadd<<<16, 256, 0, stream>>>(bih1, bhh1, bsum1, G4_);
  vadd<<<16, 256, 0, stream>>>(bih2, bhh2, bsum2, G4_);

  hipMemsetAsync(cst1, 0, (size_t)B_ * H_ * 4, stream);
  hipMemsetAsync(cst2, 0, (size_t)B_ * H_ * 4, stream);
  hipMemsetAsync(hx1h, 0, (size_t)2 * B_ * H_ * 2, stream);
  hipMemsetAsync(hx1l, 0, (size_t)2 * B_ * H_ * 2, stream);
  hipMemsetAsync(hx2h, 0, (size_t)2 * B_ * H_ * 2, stream);
  hipMemsetAsync(hx2l, 0, (size_t)2 * B_ * H_ * 2, stream);
  hipMemsetAsync(bar,  0, 4096 * 4, stream);

  const dim3 gX(32, 64);
  const dim3 gF(32, 8);

  gemmX<I_, 0, 0><<<gX, 256, 0, stream>>>(
      x, nullptr, nullptr, Wih1_hi, Wih1_lo, bsum1, xp1, G4_, 0);

  unsigned ep = 0;
  for (int c = 0; c <= NCH; ++c){
    const int mode = ((c < NCH) ? 1 : 0) | ((c >= 1) ? 2 : 0);
    const int nwg  = (mode == 3) ? 256 : 128;
    int ngrp = nwg / WPG;
    {
      void* args[] = { (void*)&mode, (void*)&ep, (void*)&ngrp,
                       (void*)&Whh1_hi, (void*)&Whh1_lo, (void*)&xp1, (void*)&cst1,
                       (void*)&hx1h, (void*)&hx1l, (void*)&h1s_hi, (void*)&h1s_lo,
                       (void*)&Whh2_hi, (void*)&Whh2_lo, (void*)&xp2, (void*)&cst2,
                       (void*)&hx2h, (void*)&hx2l, (void*)&h2s_hi, (void*)&h2s_lo,
                       (void*)&bar };
      hipLaunchCooperativeKernel((const void*)lstm_pd, dim3(nwg), dim3(512),
                                 args, 0, stream);
      ep += TC_ + 3;
    }
    if (c < NCH)
      gemmX<H_, 1, 0><<<gX, 256, 0, stream>>>(
          nullptr, h1s_hi, h1s_lo, Wih2_hi, Wih2_lo, bsum2, xp2, G4_, 0);
    if (c + 1 < NCH)
      gemmX<I_, 0, 0><<<gX, 256, 0, stream>>>(
          x, nullptr, nullptr, Wih1_hi, Wih1_lo, bsum1, xp1, G4_, (c + 1) * TC_);
    if (c >= 1)
      gemmX<H_, 1, 1><<<gF, 256, 0, stream>>>(
          nullptr, h2s_hi, h2s_lo, fcW_hi, fcW_lo, fcb, out, O_, (c - 1) * TC_);
  }
}